// Round 3
// baseline (249.846 us; speedup 1.0000x reference)
//
#include <hip/hip_runtime.h>

// TSB RNN, wave-per-row affine scan, LDS-transposed I/O, 32-VGPR streaming.
//
// Per-step linear part is anti-diagonal => over step-PAIRS the map is
// diagonal: c1 -> P*c1 + U, c2 -> Q*c2 + V (independent 1-D affine scans).
// Wave (64 lanes) owns one row; T=4096 in 4 tiles of 1024 (16 steps/lane),
// carrying (C1,C2) across tiles.
//
// OCCUPANCY MODEL (measured r0/r1/r2 A/B/C): gfx950 wave64 VGPR pool is
// 256 regs/SIMD-slot-budget: waves/SIMD = floor(256/VGPR).
//   VGPR 52..64 -> 4 waves/SIMD (Occ ~32%, 85 us); VGPR 32 -> 8 waves
//   (Occ 75%). LDS halving alone changed NOTHING => LDS never capped.
// So this version is built to fit 32 VGPR WITHOUT spilling:
//   - no xs[]/xc[] register arrays: own-row data is STREAMED
//     global->LDS (float4 at a time) and LDS->compute (float2 pairs);
//     phase 3 re-reads pairs from LDS then overwrites in place
//     (wave-private region, DS in-order => no sync needed).
//   - only Xc[16] (shared row-0 chunk, used by BOTH phases) stays in regs.
//   - a,b,oma,omb are wave-uniform => SGPRs, zero VGPR cost.
// Padding: +2 dwords per 32 elements (PADREG=1088). Each lane's 16-chunk
// is then CONTIGUOUS and 8B-aligned: chunk base cb = 16*lane + 2*(lane>>1).
// b64 accesses are bank-balanced (4 lanes per bank-pair = the wave64
// minimum), scatter/gather quads likewise.
// Round-1 lesson: (256,8) spilled only because live set was ~48 floats;
// now it is ~28, so the 32-reg budget should hold spill-free.

constexpr int T_LEN  = 4096;
constexpr int TILE   = 1024;
constexpr int NTILE  = T_LEN / TILE;         // 4
constexpr int CHUNK  = TILE / 64;            // 16 steps per lane per tile
constexpr int WPB    = 4;                    // waves per 256-thread block
constexpr int PADREG = TILE + 2 * (TILE / 32); // 1088 dwords per region

__global__ __launch_bounds__(256, 8) void tsb_scan_kernel(
    const float* __restrict__ x,       // (B, T)
    const float* __restrict__ alpha_p,
    const float* __restrict__ beta_p,
    float* __restrict__ out,           // (B, T)
    int B)
{
    __shared__ float lds[WPB * PADREG];   // 17,408 B / block

    const int tid  = threadIdx.x;
    const int wave = tid >> 6;
    const int lane = tid & 63;
    int row = blockIdx.x * WPB + wave;
    if (row >= B) row = B - 1;            // grid is exact; benign duplicate

    float* xl = &lds[wave * PADREG];      // own-row tile (reused for output)

    const float a   = alpha_p[0];         // wave-uniform -> SGPR
    const float b   = beta_p[0];
    const float oma = 1.0f - a;
    const float omb = 1.0f - b;

    // padded chunk base: elements [16*lane .. 16*lane+15] map to
    // contiguous padded addrs [cb .. cb+15] (pad lands every 32 elems).
    const int cb = 16 * lane + 2 * (lane >> 1);

    float C1 = 0.f, C2 = 0.f;             // carry across tiles

    for (int t = 0; t < NTILE; ++t) {
        const float4* xr4 = (const float4*)(x + (size_t)row * T_LEN + t * TILE);
        const float4* Xr4 = (const float4*)(x + t * TILE);

        // ---- row 0 (shared X_t quirk): per-lane contiguous 64 B chunk
        //      direct from global (4 KB, L1-hot for every wave). Kept in
        //      registers: needed by BOTH phase 1 and phase 3. ----
        float Xc[CHUNK];
#pragma unroll
        for (int m = 0; m < 4; ++m)
            *(float4*)(Xc + 4 * m) = Xr4[4 * lane + m];

        // ---- own row: coalesced global load, streamed scatter to LDS ----
#pragma unroll
        for (int i = 0; i < 4; ++i) {
            float4 vx = xr4[i * 64 + lane];
            int e0 = i * 256 + 4 * lane;        // element idx of quad start
            int bq = e0 + 2 * (e0 >> 5);        // padded addr (8B-aligned)
            *(float2*)&xl[bq]     = make_float2(vx.x, vx.y);
            *(float2*)&xl[bq + 2] = make_float2(vx.z, vx.w);
        }

        // ---- phase 1: compose 8 step-pairs into (p,u | q,v),
        //      streaming x pairs from LDS ----
        float p = 1.f, u = 0.f, q = 1.f, v = 0.f;
#pragma unroll
        for (int h = 0; h < CHUNK / 2; ++h) {
            float2 xp = *(const float2*)&xl[cb + 2 * h];
            float x1 = xp.x, x2 = xp.y;
            float X1 = Xc[2 * h], X2 = Xc[2 * h + 1];
            float nz1 = (x1 != 0.f) ? 1.f : 0.f;
            float nz2 = (x2 != 0.f) ? 1.f : 0.f;
            float k1  = (x1 != 0.f) ? oma : 1.f;
            float k2  = (x2 != 0.f) ? oma : 1.f;
            float P = omb * k1;
            float U = omb * a * nz1 * X1 + b * nz2;
            float Q = omb * k2;
            float V = b * k2 * nz1 + a * nz2 * X2;
            u = P * u + U;  p = P * p;
            v = Q * v + V;  q = Q * q;
        }

        // ---- phase 2: inclusive shuffle scan over 64 lanes ----
#pragma unroll
        for (int off = 1; off < 64; off <<= 1) {
            float pi = __shfl_up(p, off, 64);
            float ui = __shfl_up(u, off, 64);
            float qi = __shfl_up(q, off, 64);
            float vi = __shfl_up(v, off, 64);
            if (lane >= off) {
                u = p * ui + u;  p = p * pi;
                v = q * vi + v;  q = q * qi;
            }
        }
        // lane entry state = exclusive prefix applied to tile carry
        float pp = __shfl_up(p, 1, 64), up = __shfl_up(u, 1, 64);
        float qp = __shfl_up(q, 1, 64), vp = __shfl_up(v, 1, 64);
        float c1 = (lane == 0) ? C1 : (pp * C1 + up);
        float c2 = (lane == 0) ? C2 : (qp * C2 + vp);
        // tile exit carry from lane 63's inclusive map (uses OLD C1,C2)
        float p63 = __shfl(p, 63, 64), u63 = __shfl(u, 63, 64);
        float q63 = __shfl(q, 63, 64), v63 = __shfl(v, 63, 64);
        float C1n = p63 * C1 + u63;
        float C2n = q63 * C2 + v63;
        C1 = C1n;  C2 = C2n;

        // ---- phase 3: exact replay, streaming x pairs back from LDS and
        //      overwriting them with outputs in place (in-order DS) ----
#pragma unroll
        for (int h = 0; h < CHUNK / 2; ++h) {
            float2 xp = *(const float2*)&xl[cb + 2 * h];
            // step 2h
            bool  nzA = (xp.x != 0.f);
            float c2A = nzA ? (a * Xc[2 * h] + oma * c1) : c1;
            float c1A = (nzA ? b : 0.f) + omb * c2;
            // step 2h+1
            bool  nzB = (xp.y != 0.f);
            float c2B = nzB ? (a * Xc[2 * h + 1] + oma * c1A) : c1A;
            float c1B = (nzB ? b : 0.f) + omb * c2A;
            c1 = c1B;  c2 = c2B;
            *(float2*)&xl[cb + 2 * h] = make_float2(c1A * c2A, c1B * c2B);
        }

        // ---- coalesced global stores (full lines) ----
        float4* or4 = (float4*)(out + (size_t)row * T_LEN + t * TILE);
#pragma unroll
        for (int i = 0; i < 4; ++i) {
            int e0 = i * 256 + 4 * lane;
            int bq = e0 + 2 * (e0 >> 5);
            float2 w0 = *(const float2*)&xl[bq];
            float2 w1 = *(const float2*)&xl[bq + 2];
            or4[i * 64 + lane] = make_float4(w0.x, w0.y, w1.x, w1.y);
        }
    }
}

extern "C" void kernel_launch(void* const* d_in, const int* in_sizes, int n_in,
                              void* d_out, int out_size, void* d_ws, size_t ws_size,
                              hipStream_t stream) {
    const float* x     = (const float*)d_in[0];
    const float* alpha = (const float*)d_in[1];
    const float* beta  = (const float*)d_in[2];
    float* out = (float*)d_out;

    const int B = in_sizes[0] / T_LEN;   // 8192
    const int blocks = (B + WPB - 1) / WPB;
    tsb_scan_kernel<<<blocks, 64 * WPB, 0, stream>>>(x, alpha, beta, out, B);
}

// Round 4
// 234.453 us; speedup vs baseline: 1.0657x; 1.0657x over previous
//
#include <hip/hip_runtime.h>
#include <stdint.h>

// TSB RNN, wave-per-row affine scan, DMA-staged double-buffered LDS.
//
// Per-step linear part is anti-diagonal => over step-PAIRS the map is
// diagonal: c1 -> P*c1 + U, c2 -> Q*c2 + V (independent 1-D affine scans).
// Wave (64 lanes) owns one row; T=4096 in 4 tiles of 1024 (16 steps/lane),
// carrying (C1,C2) across tiles.
//
// MEASURED MODEL (r0-r3): kernel time is per-wave serial-chain bound.
// Occupancy 32% vs 69-75% (r3/r1) changes nothing (no shared pipe >40%);
// VGPR<=64 spill-free at 4 waves/SIMD is the sweet spot. So this version
// keeps 4 waves/SIMD and SHORTENS the per-wave chain:
//   - own-row staging via __builtin_amdgcn_global_load_lds (16B): no VGPR
//     round-trip, no ds_write scatter.
//   - double-buffered LDS halves + cross-tile prefetch: tile t+1's 4 DMA
//     ops are issued BEFORE waiting on tile t. s_waitcnt vmcnt(8) (in-order
//     retire) guarantees buf(t) complete while the 8 newest ops (4 X-loads
//     + 4 next-tile DMAs) stay in flight => HBM latency hidden under a full
//     tile of compute.
//   - LDS XOR-swizzle at 16B-block granularity, slot = b ^ ((b>>3)&7)
//     (involution). DMA dest is linear (HW constraint: uniform base +
//     lane*16); the SOURCE global address is per-lane pre-swizzled
//     (lane perm lam = lane ^ ((lane>>3)&7)). Chunk reads / phase-3 writes /
//     store-gather are then conflict-free ds_read/write_b128 (8 lanes per
//     bank-quad, exactly the wave64 minimum).
// Correctness of buffer reuse: tile t's store-gather ds_reads are drained
// (compiler lgkm waits) before tile t's global stores issue, which precede
// tile t+1's DMA issue in program order; DMA writes cannot land before
// issue => no LDS write-before-read race. DMA vs ds ops both touch
// addrspace(3) => compiler preserves their order.

constexpr int T_LEN = 4096;
constexpr int TILE  = 1024;          // floats per tile
constexpr int NTILE = T_LEN / TILE;  // 4
constexpr int CHUNK = TILE / 64;     // 16 steps per lane per tile
constexpr int WPB   = 4;             // waves per 256-thread block

typedef const __attribute__((address_space(1))) uint32_t* gas_ptr;
typedef __attribute__((address_space(3))) uint32_t* las_ptr;

__device__ __forceinline__ void dma16(const float* g, float* l) {
    // 16 B per lane, global (per-lane addr) -> LDS (uniform base + lane*16)
    __builtin_amdgcn_global_load_lds((gas_ptr)g, (las_ptr)l, 16, 0, 0);
}

__global__ __launch_bounds__(256) void tsb_scan_kernel(
    const float* __restrict__ x,       // (B, T)
    const float* __restrict__ alpha_p,
    const float* __restrict__ beta_p,
    float* __restrict__ out,           // (B, T)
    int B)
{
    __shared__ __align__(16) float lds[WPB * 2 * TILE];   // 32,768 B / block

    const int tid  = threadIdx.x;
    const int wave = tid >> 6;
    const int lane = tid & 63;
    int row = blockIdx.x * WPB + wave;
    if (row >= B) row = B - 1;         // grid exact; benign duplicate

    float* const buf0 = &lds[wave * 2 * TILE];   // two 4 KB halves, wave-private

    const float a   = alpha_p[0];      // wave-uniform -> SGPR
    const float b   = beta_p[0];
    const float oma = 1.0f - a;
    const float omb = 1.0f - b;

    const int lam = lane ^ ((lane >> 3) & 7);    // source-lane permutation
    const float* xrow = x + (size_t)row * T_LEN;

    // ---- prologue: DMA tile 0 into half 0 ----
    {
        const float* g = xrow + lam * 4;          // 16B block lam of tile 0
#pragma unroll
        for (int i = 0; i < 4; ++i)
            dma16(g + i * 256, buf0 + i * 256);
    }

    float C1 = 0.f, C2 = 0.f;          // carry across tiles

#pragma unroll
    for (int t = 0; t < NTILE; ++t) {
        float* const buf = buf0 + (t & 1) * TILE;

        // ---- X_t (shared row-0 quirk): per-lane 64 B chunk into regs,
        //      issued before the wait so its L1 latency hides under it ----
        float Xc[CHUNK];
        const float4* Xr4 = (const float4*)(x + t * TILE);
#pragma unroll
        for (int m = 0; m < 4; ++m)
            *(float4*)(Xc + 4 * m) = Xr4[4 * lane + m];

        // ---- prefetch: DMA tile t+1 into the other half ----
        if (t < NTILE - 1) {
            float* const nbuf = buf0 + ((t + 1) & 1) * TILE;
            const float* g = xrow + (t + 1) * TILE + lam * 4;
#pragma unroll
            for (int i = 0; i < 4; ++i)
                dma16(g + i * 256, nbuf + i * 256);
        }

        // buf(t) ready: the 8 newest VMEM ops (4 X-loads + 4 next DMAs) may
        // remain outstanding; everything older (incl. buf(t) DMAs) retired.
        asm volatile("s_waitcnt vmcnt(8)" ::: "memory");
        __builtin_amdgcn_sched_barrier(0);

        // ---- own chunk: 4 conflict-free b128 reads at swizzled slots ----
        float xc[CHUNK];
#pragma unroll
        for (int j = 0; j < 4; ++j) {
            int slot = (4 * lane + j) ^ ((lane >> 1) & 7);
            *(float4*)(xc + 4 * j) = *(const float4*)&buf[slot * 4];
        }

        // ---- phase 1: compose 8 step-pairs into (p,u | q,v) ----
        float p = 1.f, u = 0.f, q = 1.f, v = 0.f;
#pragma unroll
        for (int h = 0; h < CHUNK / 2; ++h) {
            float x1 = xc[2 * h], x2 = xc[2 * h + 1];
            float X1 = Xc[2 * h], X2 = Xc[2 * h + 1];
            float nz1 = (x1 != 0.f) ? 1.f : 0.f;
            float nz2 = (x2 != 0.f) ? 1.f : 0.f;
            float k1  = (x1 != 0.f) ? oma : 1.f;
            float k2  = (x2 != 0.f) ? oma : 1.f;
            float P = omb * k1;
            float U = omb * a * nz1 * X1 + b * nz2;
            float Q = omb * k2;
            float V = b * k2 * nz1 + a * nz2 * X2;
            u = P * u + U;  p = P * p;
            v = Q * v + V;  q = Q * q;
        }

        // ---- phase 2: inclusive shuffle scan over 64 lanes ----
#pragma unroll
        for (int off = 1; off < 64; off <<= 1) {
            float pi = __shfl_up(p, off, 64);
            float ui = __shfl_up(u, off, 64);
            float qi = __shfl_up(q, off, 64);
            float vi = __shfl_up(v, off, 64);
            if (lane >= off) {
                u = p * ui + u;  p = p * pi;
                v = q * vi + v;  q = q * qi;
            }
        }
        // lane entry state = exclusive prefix applied to tile carry
        float pp = __shfl_up(p, 1, 64), up = __shfl_up(u, 1, 64);
        float qp = __shfl_up(q, 1, 64), vp = __shfl_up(v, 1, 64);
        float c1 = (lane == 0) ? C1 : (pp * C1 + up);
        float c2 = (lane == 0) ? C2 : (qp * C2 + vp);
        // tile exit carry from lane 63's inclusive map (uses OLD C1,C2)
        float p63 = __shfl(p, 63, 64), u63 = __shfl(u, 63, 64);
        float q63 = __shfl(q, 63, 64), v63 = __shfl(v, 63, 64);
        float C1n = p63 * C1 + u63;
        float C2n = q63 * C2 + v63;
        C1 = C1n;  C2 = C2n;

        // ---- phase 3: exact replay; outputs to same swizzled slots ----
#pragma unroll
        for (int j = 0; j < 4; ++j) {
            float o[4];
#pragma unroll
            for (int k = 0; k < 2; ++k) {
                int idx = 4 * j + 2 * k;
                float xA = xc[idx], xB = xc[idx + 1];
                bool  nzA = (xA != 0.f);
                float c2A = nzA ? (a * Xc[idx] + oma * c1) : c1;
                float c1A = (nzA ? b : 0.f) + omb * c2;
                bool  nzB = (xB != 0.f);
                float c2B = nzB ? (a * Xc[idx + 1] + oma * c1A) : c1A;
                float c1B = (nzB ? b : 0.f) + omb * c2A;
                c1 = c1B;  c2 = c2B;
                o[2 * k]     = c1A * c2A;
                o[2 * k + 1] = c1B * c2B;
            }
            int slot = (4 * lane + j) ^ ((lane >> 1) & 7);
            *(float4*)&buf[slot * 4] = *(float4*)o;
        }

        // ---- store-gather (conflict-free b128) + coalesced stores ----
        float4* or4 = (float4*)(out + (size_t)row * T_LEN + t * TILE);
#pragma unroll
        for (int i = 0; i < 4; ++i) {
            int slot = i * 64 + lam;
            or4[i * 64 + lane] = *(const float4*)&buf[slot * 4];
        }
    }
}

extern "C" void kernel_launch(void* const* d_in, const int* in_sizes, int n_in,
                              void* d_out, int out_size, void* d_ws, size_t ws_size,
                              hipStream_t stream) {
    const float* x     = (const float*)d_in[0];
    const float* alpha = (const float*)d_in[1];
    const float* beta  = (const float*)d_in[2];
    float* out = (float*)d_out;

    const int B = in_sizes[0] / T_LEN;   // 8192
    const int blocks = (B + WPB - 1) / WPB;
    tsb_scan_kernel<<<blocks, 64 * WPB, 0, stream>>>(x, alpha, beta, out, B);
}